// Round 15
// baseline (171.476 us; speedup 1.0000x reference)
//
#include <hip/hip_runtime.h>
#include <math.h>

#define N 4096
#define D 512
#define TOPK 10
#define TOPK_HALF 5
#define NT 32
#define TRI_BLOCKS (NT * (NT + 1) / 2)   // 528
#define WC_BLOCKS (N * TOPK_HALF / 16)   // 1280
#define INV_N (1.0f / 4096.0f)
#define TPAD 132

typedef __bf16 bf16;
typedef __bf16 bf16x4 __attribute__((ext_vector_type(4)));
typedef __bf16 bf16x8 __attribute__((ext_vector_type(8)));
typedef float f32x4 __attribute__((ext_vector_type(4)));
typedef _Float16 f16;
typedef _Float16 f16x4 __attribute__((ext_vector_type(4)));
typedef _Float16 f16x8 __attribute__((ext_vector_type(8)));
typedef unsigned short u16;
typedef unsigned short u16x8 __attribute__((ext_vector_type(8)));
typedef unsigned int u32;

__device__ __forceinline__ void gl_lds16(const void* g, void* l) {
  __builtin_amdgcn_global_load_lds(
      (const __attribute__((address_space(1))) void*)g,
      (__attribute__((address_space(3))) void*)l, 16, 0, 0);
}

__device__ __forceinline__ float f16tof(u16 h) {
  return (float)__builtin_bit_cast(_Float16, h);
}

// merge two sorted-descending 10-lists via merge-path max/min identity (R14-verified)
__device__ __forceinline__ void merge10(const u32* A, const u32* B, u32* out) {
#pragma unroll
  for (int o = 0; o < TOPK; ++o) {
    u32 m = A[o] > B[o] ? A[o] : B[o];
#pragma unroll
    for (int p = 0; p < o; ++p) {
      u32 mn = A[p] < B[o - 1 - p] ? A[p] : B[o - 1 - p];
      m = m > mn ? m : mn;
    }
    out[o] = m;
  }
}

// ---------------- K0: L2-normalize, one wave per row (no barriers) ----------------
__global__ __launch_bounds__(256) void k_normalize3(const float* __restrict__ xs,
                                                    const float* __restrict__ xt,
                                                    bf16* __restrict__ ys,
                                                    bf16* __restrict__ yt,
                                                    float* __restrict__ rsq_s,
                                                    float* __restrict__ rsq_t,
                                                    float* __restrict__ rowsum) {
  int w = threadIdx.x >> 6, l = threadIdx.x & 63;
  int rg = blockIdx.x * 4 + w;
  int is_t = rg >> 12;
  int row = rg & (N - 1);
  const float* x = is_t ? xt : xs;
  bf16* y = is_t ? yt : ys;
  const float* xr = x + (size_t)row * D;
  float4 a = *(const float4*)(xr + l * 4);
  float4 b = *(const float4*)(xr + 256 + l * 4);
  float ss = a.x * a.x + a.y * a.y + a.z * a.z + a.w * a.w +
             b.x * b.x + b.y * b.y + b.z * b.z + b.w * b.w;
#pragma unroll
  for (int off = 32; off > 0; off >>= 1) ss += __shfl_xor(ss, off, 64);
  float inv = 1.0f / fmaxf(sqrtf(ss), 1e-12f);
  bf16x4 oa = {(bf16)(a.x * inv), (bf16)(a.y * inv), (bf16)(a.z * inv), (bf16)(a.w * inv)};
  bf16x4 ob = {(bf16)(b.x * inv), (bf16)(b.y * inv), (bf16)(b.z * inv), (bf16)(b.w * inv)};
  *(bf16x4*)(y + (size_t)row * D + l * 4) = oa;
  *(bf16x4*)(y + (size_t)row * D + 256 + l * 4) = ob;
  float s2 = 0.f;
#pragma unroll
  for (int e = 0; e < 4; ++e) {
    float fa = (float)oa[e], fb = (float)ob[e];
    s2 += fa * fa + fb * fb;
  }
#pragma unroll
  for (int off = 32; off > 0; off >>= 1) s2 += __shfl_xor(s2, off, 64);
  if (l == 0) {
    if (is_t) rsq_t[row] = s2;
    else { rsq_s[row] = s2; rowsum[row] = 0.f; }
  }
}

// ---------------- Gram: triangular BK=64 K-loop + coalesced mirrored epilogue ----------------
__global__ __launch_bounds__(256) void k_dgram3(const bf16* __restrict__ S,
                                                const bf16* __restrict__ T,
                                                const float* __restrict__ rsq_s,
                                                const float* __restrict__ rsq_t,
                                                f16* __restrict__ Gsd,
                                                f16* __restrict__ Gwp,
                                                float* __restrict__ rowsum) {
  __shared__ __align__(16) char sm[128 * TPAD * 2];
  bf16* Jb0 = (bf16*)sm;
  bf16* Jb1 = (bf16*)(sm + 8192);
  bf16* Ib0 = (bf16*)(sm + 16384);
  bf16* Ib1 = (bf16*)(sm + 24576);
  f16* tp = (f16*)sm;

  int z = blockIdx.y;
  const bf16* Y = z ? T : S;
  const float* rsq = z ? rsq_t : rsq_s;
  f16* G = z ? Gwp : Gsd;

  int t = blockIdx.x, by = 0;
  while (t >= NT - by) { t -= NT - by; ++by; }
  int bx = by + t;
  bool offdiag = (bx != by);

  int tid = threadIdx.x;
  int lane = tid & 63, w = tid >> 6;
  int wr = w >> 1, wc = w & 1;
  int quad = lane >> 4, c = lane & 15;

  const char* Jbase = (const char*)(Y + (size_t)(bx * 128) * D);
  const char* Ibase = (const char*)(Y + (size_t)(by * 128) * D);
  int r0 = tid >> 2, q0 = tid & 3;
  int r1 = (tid + 256) >> 2, q1 = (tid + 256) & 3;
  size_t so0 = (size_t)r0 * (D * 2) + q0 * 16;
  size_t so1 = (size_t)r1 * (D * 2) + q1 * 16;
  bf16* lJ0a = Jb0 + (size_t)w * 512;  bf16* lJ0b = Jb0 + (size_t)(256 + w * 64) * 8;
  bf16* lJ1a = Jb1 + (size_t)w * 512;  bf16* lJ1b = Jb1 + (size_t)(256 + w * 64) * 8;
  bf16* lI0a = Ib0 + (size_t)w * 512;  bf16* lI0b = Ib0 + (size_t)(256 + w * 64) * 8;
  bf16* lI1a = Ib1 + (size_t)w * 512;  bf16* lI1b = Ib1 + (size_t)(256 + w * 64) * 8;

  int jrow = wr * 64 + c;
  int irow = wc * 64 + c;
  int kq = quad * 8;

  f32x4 acc[4][4] = {};
  for (int k0 = 0; k0 < D; k0 += 64) {
    size_t kb = (size_t)k0 * 2;
    gl_lds16(Jbase + so0 + kb,      lJ0a);
    gl_lds16(Jbase + so1 + kb,      lJ0b);
    gl_lds16(Jbase + so0 + kb + 64, lJ1a);
    gl_lds16(Jbase + so1 + kb + 64, lJ1b);
    gl_lds16(Ibase + so0 + kb,      lI0a);
    gl_lds16(Ibase + so1 + kb,      lI0b);
    gl_lds16(Ibase + so0 + kb + 64, lI1a);
    gl_lds16(Ibase + so1 + kb + 64, lI1b);
    __syncthreads();
    {
      bf16x8 af[4], bfr[4];
#pragma unroll
      for (int u = 0; u < 4; ++u) af[u] = *(bf16x8*)&Jb0[(jrow + u * 16) * 32 + kq];
#pragma unroll
      for (int v = 0; v < 4; ++v) bfr[v] = *(bf16x8*)&Ib0[(irow + v * 16) * 32 + kq];
#pragma unroll
      for (int u = 0; u < 4; ++u)
#pragma unroll
        for (int v = 0; v < 4; ++v)
          acc[u][v] = __builtin_amdgcn_mfma_f32_16x16x32_bf16(af[u], bfr[v], acc[u][v], 0, 0, 0);
    }
    {
      bf16x8 af[4], bfr[4];
#pragma unroll
      for (int u = 0; u < 4; ++u) af[u] = *(bf16x8*)&Jb1[(jrow + u * 16) * 32 + kq];
#pragma unroll
      for (int v = 0; v < 4; ++v) bfr[v] = *(bf16x8*)&Ib1[(irow + v * 16) * 32 + kq];
#pragma unroll
      for (int u = 0; u < 4; ++u)
#pragma unroll
        for (int v = 0; v < 4; ++v)
          acc[u][v] = __builtin_amdgcn_mfma_f32_16x16x32_bf16(af[u], bfr[v], acc[u][v], 0, 0, 0);
    }
    __syncthreads();
  }

#pragma unroll
  for (int v = 0; v < 4; ++v) {
    int il = wc * 64 + v * 16 + c;
    int ig = by * 128 + il;
    float ri = rsq[ig];
    float rsv = 0.f;
#pragma unroll
    for (int u = 0; u < 4; ++u) {
      int jl0 = wr * 64 + u * 16 + quad * 4;
      int jb0i = bx * 128 + jl0;
      float4 rj = *(const float4*)(rsq + jb0i);
      const float* rjp = (const float*)&rj;
      f32x4 a = acc[u][v];
      f16x4 st;
      if (z == 0) {
#pragma unroll
        for (int reg = 0; reg < 4; ++reg) {
          float sq = fmaxf(ri + rjp[reg] - 2.0f * a[reg], 0.0f);
          float val = sqrtf(sq);
          st[reg] = (_Float16)val;
          rsv += val;
        }
      } else {
#pragma unroll
        for (int reg = 0; reg < 4; ++reg) {
          float sq = fmaxf(ri + rjp[reg] - 2.0f * a[reg], 0.0f);
          st[reg] = (_Float16)expf(-sq);
        }
      }
      *(f16x4*)(G + (size_t)ig * N + jb0i) = st;
      if (offdiag) {
#pragma unroll
        for (int reg = 0; reg < 4; ++reg) tp[(jl0 + reg) * TPAD + il] = st[reg];
      }
    }
    if (z == 0) {
      rsv += __shfl_xor(rsv, 16, 64);
      rsv += __shfl_xor(rsv, 32, 64);
      if (lane < 16) atomicAdd(&rowsum[ig], rsv);
    }
  }

  if (offdiag) {
    __syncthreads();
    int rloc = tid >> 4;
    int cseg = tid & 15;
#pragma unroll
    for (int it = 0; it < 8; ++it) {
      int jl = it * 16 + rloc;
      int jg = bx * 128 + jl;
      f16x8 v8 = *(f16x8*)&tp[jl * TPAD + cseg * 8];
      *(f16x8*)(G + (size_t)jg * N + by * 128 + cseg * 8) = v8;
      if (z == 0) {
        float csum = 0.f;
#pragma unroll
        for (int e = 0; e < 8; ++e) csum += (float)v8[e];
        csum += __shfl_xor(csum, 1, 64);
        csum += __shfl_xor(csum, 2, 64);
        csum += __shfl_xor(csum, 4, 64);
        csum += __shfl_xor(csum, 8, 64);
        if (cseg == 0) atomicAdd(&rowsum[jg], csum);
      }
    }
  }
}

// ---------------- Row pass: half-row per block (8192 x 128) ----------------
__global__ __launch_bounds__(128) void k_rowpass(const f16* __restrict__ Gs,
                                                 const f16* __restrict__ Gw,
                                                 const int* __restrict__ ids,
                                                 const float* __restrict__ rowsum,
                                                 u32* __restrict__ cand2,
                                                 double* __restrict__ pd) {
  __shared__ u32 lds[128 * TOPK];  // 5 KB
  __shared__ double dred[2];
  int b = blockIdx.x;
  int i = b >> 1, half = b & 1;
  int base = half * 2048;
  int tid = threadIdx.x;
  int idi = ids[i];
  float invm = 1.0f / (rowsum[i] * INV_N);
  const u16* srow = (const u16*)(Gs + (size_t)i * N + base);
  const u16* wrow = (const u16*)(Gw + (size_t)i * N + base);
  u32 key[16];
  float dsum = 0.f;
  int j0 = tid * 16;
#pragma unroll
  for (int h = 0; h < 2; ++h) {
    int jb = j0 + h * 8;
    u16x8 sv = *(const u16x8*)(srow + jb);
    u16x8 wv = *(const u16x8*)(wrow + jb);
    int4 id0 = *(const int4*)(ids + base + jb);
    int4 id1 = *(const int4*)(ids + base + jb + 4);
    const int* idp = (const int*)&id0;
    const int* idp1 = (const int*)&id1;
#pragma unroll
    for (int e = 0; e < 8; ++e) {
      int jg = base + jb + e;
      u16 hw = wv[e];
      float wp = f16tof(hw);
      if (jg != i) {
        float sdn = f16tof(sv[e]) * invm;
        float r = fmaxf(1.0f - sdn, 0.0f); r *= r;
        dsum += r + 0.5f * wp * (sdn * sdn - r);
      }
      int idj = (e < 4) ? idp[e] : idp1[e - 4];
      u16 hk = (idj == idi) ? (u16)0x3C00 : hw;
      key[h * 8 + e] = ((u32)hk << 16) | (u32)(4095 - jg);
    }
  }
  // bitonic sort-16 descending (branch-free)
#pragma unroll
  for (int kk = 2; kk <= 16; kk <<= 1) {
#pragma unroll
    for (int jj = kk >> 1; jj > 0; jj >>= 1) {
#pragma unroll
      for (int ii = 0; ii < 16; ++ii) {
        int ll = ii ^ jj;
        if (ll > ii) {
          bool desc = ((ii & kk) == 0);
          u32 a = key[ii], bb = key[ll];
          bool sw = desc ? (a < bb) : (a > bb);
          key[ii] = sw ? bb : a;
          key[ll] = sw ? a : bb;
        }
      }
    }
  }
  double dl = (double)dsum;
  for (int off = 32; off > 0; off >>= 1) dl += __shfl_down(dl, off, 64);
  if ((tid & 63) == 0) dred[tid >> 6] = dl;
#pragma unroll
  for (int o = 0; o < TOPK; ++o) lds[tid * TOPK + o] = key[o];
  __syncthreads();
  for (int off = 64; off >= 1; off >>= 1) {
    if (tid < off) {
      u32 A[TOPK], B[TOPK], out[TOPK];
#pragma unroll
      for (int o = 0; o < TOPK; ++o) {
        A[o] = lds[tid * TOPK + o];
        B[o] = lds[(tid + off) * TOPK + o];
      }
      merge10(A, B, out);
#pragma unroll
      for (int o = 0; o < TOPK; ++o) lds[tid * TOPK + o] = out[o];
    }
    __syncthreads();
  }
  if (tid == 0) {
#pragma unroll
    for (int o = 0; o < TOPK; ++o) cand2[(size_t)b * TOPK + o] = lds[o];
    pd[b] = dred[0] + dred[1];
  }
}

// ---------------- buildV: merge half-lists + mutual-kNN ----------------
__global__ __launch_bounds__(64) void k_buildV(const u32* __restrict__ cand2,
                                               int* __restrict__ topk,
                                               int* __restrict__ L,
                                               int* __restrict__ cnt) {
  int i = blockIdx.x * 64 + threadIdx.x;
  if (i >= N) return;
  u32 A[TOPK], B[TOPK], my[TOPK];
#pragma unroll
  for (int o = 0; o < TOPK; ++o) {
    A[o] = cand2[(size_t)(i * 2) * TOPK + o];
    B[o] = cand2[(size_t)(i * 2 + 1) * TOPK + o];
  }
  merge10(A, B, my);
  int tk[TOPK];
#pragma unroll
  for (int o = 0; o < TOPK; ++o) {
    tk[o] = 4095 - (int)(my[o] & 0xFFFu);
    topk[i * TOPK + o] = tk[o];
  }
  int c = 0;
  for (int r = 0; r < TOPK; ++r) {
    int j = tk[r];
    u32 JA[TOPK], JB[TOPK], jt[TOPK];
#pragma unroll
    for (int o = 0; o < TOPK; ++o) {
      JA[o] = cand2[(size_t)(j * 2) * TOPK + o];
      JB[o] = cand2[(size_t)(j * 2 + 1) * TOPK + o];
    }
    merge10(JA, JB, jt);
    bool mut = false;
#pragma unroll
    for (int q = 0; q < TOPK; ++q) mut |= ((4095 - (int)(jt[q] & 0xFFFu)) == i);
    if (mut) L[i * TOPK + c++] = j;
  }
  cnt[i] = c;
}

// ---------------- sparse W_C loss: one 16-lane group per task, sd from Gsd ----------------
__global__ __launch_bounds__(256) void k_wc(const int* __restrict__ topk,
                                            const int* __restrict__ L,
                                            const int* __restrict__ cnt,
                                            const f16* __restrict__ Gsd,
                                            const float* __restrict__ rowsum,
                                            double* __restrict__ pw) {
  __shared__ double red[16];
  int tid = threadIdx.x;
  int grp = tid >> 4;
  int gl = tid & 15;
  int task = blockIdx.x * 16 + grp;
  int i = task / TOPK_HALF, m = task % TOPK_HALF;
  int r = topk[i * TOPK + m];
  int cr = cnt[r];
  float invmi = 1.0f / (rowsum[i] * INV_N);
  int lval = (gl < cr) ? L[r * TOPK + gl] : -1;
  int Lr[TOPK];
#pragma unroll
  for (int a = 0; a < TOPK; ++a) Lr[a] = __shfl(lval, a, 16);
  float contrib = 0.f;
  if (gl < cr) {
    int j = lval;
    if (j != i) {
      int cj = cnt[j];
      float mj = rowsum[j] * INV_N;
      float sr_ = f16tof(((const u16*)Gsd)[(size_t)i * N + j]);
      int lj[TOPK];
#pragma unroll
      for (int b = 0; b < TOPK; ++b) lj[b] = L[j * TOPK + b];
      int vv = 0;
#pragma unroll
      for (int b = 0; b < TOPK; ++b) {
        if (b < cj) {
#pragma unroll
          for (int a = 0; a < TOPK; ++a)
            vv += ((a < cr) && (lj[b] == Lr[a])) ? 1 : 0;
        }
      }
      float denom = (float)(cr > 1 ? cr : 1);
      float wgt = (float)vv / denom;
      float sdij = sr_ * invmi;
      float sdji = sr_ / mj;
      float Rij = fmaxf(1.0f - sdij, 0.0f); Rij *= Rij;
      float Rji = fmaxf(1.0f - sdji, 0.0f); Rji *= Rji;
      float Fij = sdij * sdij - Rij;
      float Fji = sdji * sdji - Rji;
      contrib = wgt * (Fij + Fji);
    }
  }
  double local = (double)contrib;
  local += __shfl_xor(local, 1, 16);
  local += __shfl_xor(local, 2, 16);
  local += __shfl_xor(local, 4, 16);
  local += __shfl_xor(local, 8, 16);
  if (gl == 0) red[grp] = local;
  __syncthreads();
  if (tid == 0) {
    double s = 0.0;
#pragma unroll
    for (int g = 0; g < 16; ++g) s += red[g];
    pw[blockIdx.x] = s * (1.0 / 20.0);
  }
}

// ---------------- final reduce ----------------
__global__ __launch_bounds__(256) void k_final(const double* __restrict__ pd,
                                               const double* __restrict__ pw,
                                               float* __restrict__ out) {
  int tid = threadIdx.x;
  double s = 0.0;
  for (int i = tid; i < 2 * N; i += 256) s += pd[i];
  for (int i = tid; i < WC_BLOCKS; i += 256) s += pw[i];
  for (int off = 32; off > 0; off >>= 1) s += __shfl_down(s, off, 64);
  __shared__ double red[4];
  if ((tid & 63) == 0) red[tid >> 6] = s;
  __syncthreads();
  if (tid == 0)
    out[0] = (float)((red[0] + red[1] + red[2] + red[3]) /
                     ((double)N * (double)(N - 1)));
}

extern "C" void kernel_launch(void* const* d_in, const int* in_sizes, int n_in,
                              void* d_out, int out_size, void* d_ws, size_t ws_size,
                              hipStream_t stream) {
  const float* s_emb = (const float*)d_in[0];
  const float* t_emb = (const float*)d_in[1];
  const int* ids = (const int*)d_in[2];
  float* out = (float*)d_out;

  char* ws = (char*)d_ws;
  size_t off = 0;
  bf16* snorm = (bf16*)(ws + off); off += (size_t)N * D * 2;        // 4 MB
  bf16* tnorm = (bf16*)(ws + off); off += (size_t)N * D * 2;        // 4 MB
  f16*  Gsd   = (f16*)(ws + off);  off += (size_t)N * N * 2;        // 32 MB
  f16*  Gwp   = (f16*)(ws + off);  off += (size_t)N * N * 2;        // 32 MB
  float* rsq_s = (float*)(ws + off); off += (size_t)N * 4;
  float* rsq_t = (float*)(ws + off); off += (size_t)N * 4;
  float* rowsum= (float*)(ws + off); off += (size_t)N * 4;
  int*   topk  = (int*)(ws + off);   off += (size_t)N * TOPK * 4;
  int*   L     = (int*)(ws + off);   off += (size_t)N * TOPK * 4;
  int*   cnt   = (int*)(ws + off);   off += (size_t)N * 4;
  off = (off + 15) & ~(size_t)15;
  u32*  cand2  = (u32*)(ws + off);   off += (size_t)N * 2 * TOPK * 4;  // 327 KB
  double* pd   = (double*)(ws + off); off += (size_t)N * 2 * 8;
  double* pw   = (double*)(ws + off); off += (size_t)WC_BLOCKS * 8;

  k_normalize3<<<2048, 256, 0, stream>>>(s_emb, t_emb, snorm, tnorm,
                                         rsq_s, rsq_t, rowsum);
  k_dgram3<<<dim3(TRI_BLOCKS, 2), 256, 0, stream>>>(snorm, tnorm, rsq_s, rsq_t,
                                                    Gsd, Gwp, rowsum);
  k_rowpass<<<2 * N, 128, 0, stream>>>(Gsd, Gwp, ids, rowsum, cand2, pd);
  k_buildV<<<N / 64, 64, 0, stream>>>(cand2, topk, L, cnt);
  k_wc<<<WC_BLOCKS, 256, 0, stream>>>(topk, L, cnt, Gsd, rowsum, pw);
  k_final<<<1, 256, 0, stream>>>(pd, pw, out);
}